// Round 1
// baseline (458.677 us; speedup 1.0000x reference)
//
#include <hip/hip_runtime.h>
#include <stdint.h>

#define Hdim 512
#define Bdim 128
#define Ldim 512
#define Vdim 2048

using f32x4  = float  __attribute__((ext_vector_type(4)));
using bf16x8 = __bf16 __attribute__((ext_vector_type(8)));

__device__ inline unsigned short f2bf(float x) {
  uint32_t u = __float_as_uint(x);
  u += 0x7fffu + ((u >> 16) & 1u);   // round-to-nearest-even
  return (unsigned short)(u >> 16);
}
__device__ inline float fast_tanh(float x) {
  // tanh(x) = 1 - 2/(exp(2x)+1); saturates correctly for |x| large
  return 1.0f - 2.0f / (__expf(2.0f * x) + 1.0f);
}
__device__ inline float fast_sig(float x) {
  return 1.0f / (1.0f + __expf(-x));
}

// ---------- mask dtype detection: byte-mask has nonzero bytes at pos%4!=0 ----------
__global__ void detect_mask_kernel(const uint8_t* __restrict__ m, int nbytes, int* flag) {
  int i = blockIdx.x * 256 + threadIdx.x;
  if (i < nbytes && (i & 3) && m[i]) atomicOr(flag, 1);
}

// ---------- emb gather -> x0[:, 0:H] ----------
__global__ void gather_emb_kernel(const float* __restrict__ wdv, const int* __restrict__ ids,
                                  float* __restrict__ x0) {
  int idx = blockIdx.x * 256 + threadIdx.x;  // 65536
  int b = idx >> 9, i = idx & 511;
  x0[b * 1024 + i] = wdv[(size_t)b * (Vdim * Hdim) + (size_t)ids[b] * Hdim + i];
}

// ---------- generic small fp32 GEMM: C[m][n] = act(sum_k X[m][k]*W[n][k] + bias[n]) ----------
// grid: (N/32, M/32), 256 threads, tiles 32x32, K%16==0
__global__ void gemm_f32_kernel(const float* __restrict__ X, int ldx,
                                const float* __restrict__ W, int ldw,
                                const float* __restrict__ bias,
                                float* __restrict__ C, int ldc,
                                int K, int act) {
  __shared__ float Xs[16][32];
  __shared__ float Ws[16][32];
  int t = threadIdx.x;
  int tx = t & 15, ty = t >> 4;
  int m0 = blockIdx.y * 32, n0 = blockIdx.x * 32;
  int srow = t >> 3;          // 0..31
  int skp  = (t & 7) * 2;     // 0..14
  float acc00 = 0.f, acc01 = 0.f, acc10 = 0.f, acc11 = 0.f;
  for (int k0 = 0; k0 < K; k0 += 16) {
    float2 xv = *(const float2*)(X + (size_t)(m0 + srow) * ldx + k0 + skp);
    float2 wv = *(const float2*)(W + (size_t)(n0 + srow) * ldw + k0 + skp);
    Xs[skp][srow] = xv.x; Xs[skp + 1][srow] = xv.y;
    Ws[skp][srow] = wv.x; Ws[skp + 1][srow] = wv.y;
    __syncthreads();
#pragma unroll
    for (int k = 0; k < 16; ++k) {
      float x0v = Xs[k][ty * 2], x1v = Xs[k][ty * 2 + 1];
      float w0  = Ws[k][tx * 2], w1  = Ws[k][tx * 2 + 1];
      acc00 += x0v * w0; acc01 += x0v * w1;
      acc10 += x1v * w0; acc11 += x1v * w1;
    }
    __syncthreads();
  }
  float vb0 = bias[n0 + tx * 2], vb1 = bias[n0 + tx * 2 + 1];
  float o00 = acc00 + vb0, o01 = acc01 + vb1, o10 = acc10 + vb0, o11 = acc11 + vb1;
  if (act) { o00 = tanhf(o00); o01 = tanhf(o01); o10 = tanhf(o10); o11 = tanhf(o11); }
  float* Cr0 = C + (size_t)(m0 + ty * 2) * ldc + n0 + tx * 2;
  float* Cr1 = Cr0 + ldc;
  Cr0[0] = o00; Cr0[1] = o01;
  Cr1[0] = o10; Cr1[1] = o11;
}

// ---------- fused attention energy: bf16 MFMA GEMM + tanh + score-dot -> atomic scores ----------
// grid 2048 = 512 M-blocks x 4 N-blocks; block 256 = 4 waves (2x2 of 64x64)
__global__ __launch_bounds__(256, 2)
void attn_scores_kernel(const float* __restrict__ enc,
                        const float* __restrict__ attn_W,
                        const float* __restrict__ qW,
                        const float* __restrict__ score_W,
                        float* __restrict__ scores) {
  __shared__ __align__(16) unsigned short As[128][40];  // pad 32->40 bf16 (80B rows)
  __shared__ __align__(16) unsigned short Bs[128][40];
  int bx = blockIdx.x;
  int mb = bx >> 2, nb = bx & 3;
  int t = threadIdx.x;
  int lane = t & 63, wid = t >> 6;
  int wm = wid >> 1, wn = wid & 1;
  int m0 = mb * 128;   // rows of enc_flat [L*B, H]; l = mb, b = local row
  int o0 = nb * 128;

  f32x4 acc[4][4];
#pragma unroll
  for (int i = 0; i < 4; ++i)
#pragma unroll
    for (int j = 0; j < 4; ++j) acc[i][j] = (f32x4){0.f, 0.f, 0.f, 0.f};

  int srow = t >> 3;         // 0..31
  int skq  = (t & 7) * 4;    // 0,4,...,28
  int fr  = lane & 15;
  int kof = (lane >> 4) * 8;

  for (int kt = 0; kt < 512; kt += 32) {
#pragma unroll
    for (int p = 0; p < 4; ++p) {
      int row = srow + p * 32;
      float4 av = *(const float4*)(enc + (size_t)(m0 + row) * 512 + kt + skq);
      float4 bv = *(const float4*)(attn_W + (size_t)(o0 + row) * 1024 + 512 + kt + skq);
      ushort4 ap, bp;
      ap.x = f2bf(av.x); ap.y = f2bf(av.y); ap.z = f2bf(av.z); ap.w = f2bf(av.w);
      bp.x = f2bf(bv.x); bp.y = f2bf(bv.y); bp.z = f2bf(bv.z); bp.w = f2bf(bv.w);
      *(ushort4*)&As[row][skq] = ap;
      *(ushort4*)&Bs[row][skq] = bp;
    }
    __syncthreads();
    bf16x8 a[4], b[4];
#pragma unroll
    for (int mi = 0; mi < 4; ++mi) a[mi] = *(const bf16x8*)&As[wm * 64 + mi * 16 + fr][kof];
#pragma unroll
    for (int ni = 0; ni < 4; ++ni) b[ni] = *(const bf16x8*)&Bs[wn * 64 + ni * 16 + fr][kof];
#pragma unroll
    for (int mi = 0; mi < 4; ++mi)
#pragma unroll
      for (int ni = 0; ni < 4; ++ni)
        acc[mi][ni] = __builtin_amdgcn_mfma_f32_16x16x32_bf16(a[mi], b[ni], acc[mi][ni], 0, 0, 0);
    __syncthreads();
  }

  // epilogue: + qW[b][o], tanh, *score_W[o], reduce over o, atomicAdd into scores[b][l]
  int g = lane >> 4;   // row group
  int l = mb;
#pragma unroll
  for (int mi = 0; mi < 4; ++mi) {
    float rs0 = 0.f, rs1 = 0.f, rs2 = 0.f, rs3 = 0.f;
#pragma unroll
    for (int ni = 0; ni < 4; ++ni) {
      int o = o0 + wn * 64 + ni * 16 + fr;
      float sw = score_W[o];
      int brow = wm * 64 + mi * 16 + g * 4;   // = b for reg 0
      rs0 += sw * fast_tanh(acc[mi][ni][0] + qW[(brow + 0) * 512 + o]);
      rs1 += sw * fast_tanh(acc[mi][ni][1] + qW[(brow + 1) * 512 + o]);
      rs2 += sw * fast_tanh(acc[mi][ni][2] + qW[(brow + 2) * 512 + o]);
      rs3 += sw * fast_tanh(acc[mi][ni][3] + qW[(brow + 3) * 512 + o]);
    }
#pragma unroll
    for (int d = 1; d < 16; d <<= 1) {
      rs0 += __shfl_xor(rs0, d);
      rs1 += __shfl_xor(rs1, d);
      rs2 += __shfl_xor(rs2, d);
      rs3 += __shfl_xor(rs3, d);
    }
    if (fr < 4) {
      float v = (fr == 0) ? rs0 : (fr == 1) ? rs1 : (fr == 2) ? rs2 : rs3;
      int b = wm * 64 + mi * 16 + g * 4 + fr;
      atomicAdd(&scores[b * Ldim + l], v);
    }
  }
}

// ---------- masked softmax over L, in place ----------
__global__ void softmax_kernel(float* __restrict__ scores, const void* __restrict__ maskp,
                               const int* __restrict__ flag) {
  int b = blockIdx.x, t = threadIdx.x;  // 256 threads
  bool isbyte = (*flag != 0);
  int l0 = t, l1 = t + 256;
  float s0 = scores[b * 512 + l0], s1 = scores[b * 512 + l1];
  bool m0, m1;
  if (isbyte) {
    m0 = ((const uint8_t*)maskp)[b * 512 + l0] != 0;
    m1 = ((const uint8_t*)maskp)[b * 512 + l1] != 0;
  } else {
    m0 = ((const int*)maskp)[b * 512 + l0] != 0;
    m1 = ((const int*)maskp)[b * 512 + l1] != 0;
  }
  float v0 = m0 ? -1e12f : s0;
  float v1 = m1 ? -1e12f : s1;
  __shared__ float redm[4];
  __shared__ float reds[4];
  float mx = fmaxf(v0, v1);
#pragma unroll
  for (int d = 1; d < 64; d <<= 1) mx = fmaxf(mx, __shfl_xor(mx, d));
  if ((t & 63) == 0) redm[t >> 6] = mx;
  __syncthreads();
  mx = fmaxf(fmaxf(redm[0], redm[1]), fmaxf(redm[2], redm[3]));
  float e0 = __expf(v0 - mx), e1 = __expf(v1 - mx);
  float sm = e0 + e1;
#pragma unroll
  for (int d = 1; d < 64; d <<= 1) sm += __shfl_xor(sm, d);
  if ((t & 63) == 0) reds[t >> 6] = sm;
  __syncthreads();
  sm = reds[0] + reds[1] + reds[2] + reds[3];
  float inv = 1.0f / sm;
  scores[b * 512 + l0] = e0 * inv;
  scores[b * 512 + l1] = e1 * inv;
}

// ---------- context[b][h] = sum_l aw[b][l] * enc[l][b][h] -> x0[:, H:2H] ----------
__global__ void context_kernel(const float* __restrict__ enc, const float* __restrict__ aw,
                               float* __restrict__ x0) {
  int b = blockIdx.x, t = threadIdx.x;  // 256 threads
  __shared__ float w[512];
  w[t] = aw[b * 512 + t];
  w[t + 256] = aw[b * 512 + t + 256];
  __syncthreads();
  float a0 = 0.f, a1 = 0.f;
  for (int l = 0; l < 512; ++l) {
    float wl = w[l];
    if (wl != 0.0f) {  // block-uniform branch; skips masked positions
      const float* e = enc + (size_t)l * 65536 + b * 512;
      a0 += wl * e[t];
      a1 += wl * e[t + 256];
    }
  }
  x0[b * 1024 + 512 + t] = a0;
  x0[b * 1024 + 512 + t + 256] = a1;
}

// ---------- GRU pointwise combine (torch gate order r,z,n) ----------
__global__ void gru_combine_kernel(const float* __restrict__ gi, const float* __restrict__ gh,
                                   const float* __restrict__ hprev, float* __restrict__ h) {
  int idx = blockIdx.x * 256 + threadIdx.x;  // 65536
  int b = idx >> 9, o = idx & 511;
  const float* gib = gi + (size_t)b * 1536;
  const float* ghb = gh + (size_t)b * 1536;
  float r = fast_sig(gib[o] + ghb[o]);
  float z = fast_sig(gib[512 + o] + ghb[512 + o]);
  float n = tanhf(gib[1024 + o] + r * ghb[1024 + o]);
  h[idx] = (1.0f - z) * n + z * hprev[idx];
}

// ---------- c1 = [h1, context] ----------
__global__ void concat_kernel(const float* __restrict__ h1, const float* __restrict__ x0,
                              float* __restrict__ c1) {
  int idx = blockIdx.x * 256 + threadIdx.x;  // 131072
  int b = idx >> 10, i = idx & 1023;
  c1[idx] = (i < 512) ? h1[b * 512 + i] : x0[b * 1024 + i];
}

extern "C" void kernel_launch(void* const* d_in, const int* in_sizes, int n_in,
                              void* d_out, int out_size, void* d_ws, size_t ws_size,
                              hipStream_t stream) {
  const int*   ids    = (const int*)  d_in[0];
  const float* lh     = (const float*)d_in[1];   // [2,B,H]
  const float* wdv    = (const float*)d_in[2];
  const float* enc    = (const float*)d_in[3];   // [L,B,H]
  const void*  mask   = d_in[4];
  const float* attn_W = (const float*)d_in[5];   // [H, 2H]
  const float* attn_b = (const float*)d_in[6];
  const float* scW    = (const float*)d_in[7];   // [1, H]
  const float* cat_W  = (const float*)d_in[8];   // [H, 2H]
  const float* cat_b  = (const float*)d_in[9];
  const float* W_ih0  = (const float*)d_in[10];
  const float* W_hh0  = (const float*)d_in[11];
  const float* b_ih0  = (const float*)d_in[12];
  const float* b_hh0  = (const float*)d_in[13];
  const float* W_ih1  = (const float*)d_in[14];
  const float* W_hh1  = (const float*)d_in[15];
  const float* b_ih1  = (const float*)d_in[16];
  const float* b_hh1  = (const float*)d_in[17];

  float* out = (float*)d_out;       // [B,H] output
  float* h0  = out + 65536;         // hidden[0]
  float* h1  = out + 131072;        // hidden[1]

  float* ws     = (float*)d_ws;
  float* scores = ws;                // 65536 (becomes aw in place)
  int*   flag   = (int*)(ws + 65536);
  float* qW     = ws + 65552;        // 65536
  float* x0     = ws + 131088;       // 131072  [emb | context]
  float* gi0    = ws + 262160;       // 196608
  float* gh0    = ws + 458768;       // 196608
  float* gi1    = ws + 655376;       // 196608
  float* gh1    = ws + 851984;       // 196608
  float* c1     = ws + 1048592;      // 131072  (end: 1179664 floats ~ 4.7 MB)

  const float* q = lh + 65536;       // last_hidden[-1]

  hipMemsetAsync(scores, 0, (65536 + 16) * sizeof(float), stream);
  detect_mask_kernel<<<256, 256, 0, stream>>>((const uint8_t*)mask, Bdim * Ldim, flag);
  gather_emb_kernel<<<256, 256, 0, stream>>>(wdv, ids, x0);
  // qW = q @ attn_W[:, :H]^T + attn_b
  gemm_f32_kernel<<<dim3(16, 4), 256, 0, stream>>>(q, 512, attn_W, 1024, attn_b, qW, 512, 512, 0);
  attn_scores_kernel<<<2048, 256, 0, stream>>>(enc, attn_W, qW, scW, scores);
  softmax_kernel<<<128, 256, 0, stream>>>(scores, mask, flag);
  context_kernel<<<128, 256, 0, stream>>>(enc, scores, x0);
  // layer 0
  gemm_f32_kernel<<<dim3(48, 4), 256, 0, stream>>>(x0, 1024, W_ih0, 1024, b_ih0, gi0, 1536, 1024, 0);
  gemm_f32_kernel<<<dim3(48, 4), 256, 0, stream>>>(lh, 512, W_hh0, 512, b_hh0, gh0, 1536, 512, 0);
  gru_combine_kernel<<<256, 256, 0, stream>>>(gi0, gh0, lh, h0);
  // layer 1
  gemm_f32_kernel<<<dim3(48, 4), 256, 0, stream>>>(h0, 512, W_ih1, 512, b_ih1, gi1, 1536, 512, 0);
  gemm_f32_kernel<<<dim3(48, 4), 256, 0, stream>>>(q, 512, W_hh1, 512, b_hh1, gh1, 1536, 512, 0);
  gru_combine_kernel<<<256, 256, 0, stream>>>(gi1, gh1, q, h1);
  // output = tanh([h1, context] @ cat_W^T + cat_b)
  concat_kernel<<<512, 256, 0, stream>>>(h1, x0, c1);
  gemm_f32_kernel<<<dim3(16, 4), 256, 0, stream>>>(c1, 1024, cat_W, 1024, cat_b, out, 512, 1024, 1);
}

// Round 2
// 428.200 us; speedup vs baseline: 1.0712x; 1.0712x over previous
//
#include <hip/hip_runtime.h>
#include <stdint.h>

#define Hdim 512
#define Bdim 128
#define Ldim 512
#define Vdim 2048

typedef unsigned short u16;
using f32x4  = float  __attribute__((ext_vector_type(4)));
using bf16x8 = __bf16 __attribute__((ext_vector_type(8)));

__device__ inline u16 f2bf(float x) {
  uint32_t u = __float_as_uint(x);
  u += 0x7fffu + ((u >> 16) & 1u);   // RNE
  return (u16)(u >> 16);
}
__device__ inline float bfhi2f(uint32_t hi16) { return __uint_as_float(hi16 << 16); }
__device__ inline float fast_tanh(float x) {
  return 1.0f - 2.0f / (__expf(2.0f * x) + 1.0f);
}
__device__ inline float fast_sig(float x) { return 1.0f / (1.0f + __expf(-x)); }

__device__ inline void gload_lds16(const u16* g, u16* l) {
  auto gp = (const __attribute__((address_space(1))) uint32_t*)(uintptr_t)g;
  auto lp = (__attribute__((address_space(3))) uint32_t*)(uintptr_t)l;
  __builtin_amdgcn_global_load_lds(gp, lp, 16, 0, 0);
}

__device__ inline bf16x8 pack_bf8(float4 a, float4 b) {
  union { u16 u[8]; bf16x8 v; } r;
  r.u[0] = f2bf(a.x); r.u[1] = f2bf(a.y); r.u[2] = f2bf(a.z); r.u[3] = f2bf(a.w);
  r.u[4] = f2bf(b.x); r.u[5] = f2bf(b.y); r.u[6] = f2bf(b.z); r.u[7] = f2bf(b.w);
  return r.v;
}

// ---------- mask dtype detection ----------
__global__ void detect_mask_kernel(const uint8_t* __restrict__ m, int nbytes, int* flag) {
  int i = blockIdx.x * 256 + threadIdx.x;
  if (i < nbytes && (i & 3) && m[i]) atomicOr(flag, 1);
}

// ---------- enc f32 -> bf16 ----------
__global__ void convert_enc_kernel(const float* __restrict__ src, u16* __restrict__ dst) {
  size_t i = ((size_t)blockIdx.x * 256 + threadIdx.x) * 8;  // 33554432 total
  float4 a = *(const float4*)(src + i);
  float4 b = *(const float4*)(src + i + 4);
  ushort4 u0, u1;
  u0.x = f2bf(a.x); u0.y = f2bf(a.y); u0.z = f2bf(a.z); u0.w = f2bf(a.w);
  u1.x = f2bf(b.x); u1.y = f2bf(b.y); u1.z = f2bf(b.z); u1.w = f2bf(b.w);
  *(ushort4*)(dst + i) = u0;
  *(ushort4*)(dst + i + 4) = u1;
}

// ---------- weight prep: bf16 arena + fused GRU layouts + fused bias ----------
// arena: Whid@0 (512x512), Wenc@262144 (512x512), Wcat@524288 (512x1024),
//        Wg0@1048576 (2048x1536), Wg1@4194304 (2048x1024)   total 6291456
__global__ void prep_weights_kernel(const float* __restrict__ attn_W, const float* __restrict__ cat_W,
                                    const float* __restrict__ W_ih0, const float* __restrict__ W_hh0,
                                    const float* __restrict__ W_ih1, const float* __restrict__ W_hh1,
                                    const float* __restrict__ b_ih0, const float* __restrict__ b_hh0,
                                    const float* __restrict__ b_ih1, const float* __restrict__ b_hh1,
                                    u16* __restrict__ arena, float* __restrict__ bias0,
                                    float* __restrict__ bias1) {
  int gid = blockIdx.x * 256 + threadIdx.x;
  if (blockIdx.x >= 6144) {  // bias blocks
    int r = gid - 6144 * 256;
    if (r < 2048) {
      int o = r;
      bias0[o] = (o < 1024) ? b_ih0[o] + b_hh0[o] : (o < 1536 ? b_ih0[o] : b_hh0[o - 512]);
    } else if (r < 4096) {
      int o = r - 2048;
      bias1[o] = (o < 1024) ? b_ih1[o] + b_hh1[o] : (o < 1536 ? b_ih1[o] : b_hh1[o - 512]);
    }
    return;
  }
  int e = gid * 4;
  float4 v = {0.f, 0.f, 0.f, 0.f};
  if (e < 262144) {                       // Whid = attn_W[:, :512]
    int o = e >> 9, k = e & 511;
    v = *(const float4*)(attn_W + (size_t)o * 1024 + k);
  } else if (e < 524288) {                // Wenc = attn_W[:, 512:]
    int e2 = e - 262144; int o = e2 >> 9, k = e2 & 511;
    v = *(const float4*)(attn_W + (size_t)o * 1024 + 512 + k);
  } else if (e < 1048576) {               // Wcat
    int e2 = e - 524288; int o = e2 >> 10, k = e2 & 1023;
    v = *(const float4*)(cat_W + (size_t)o * 1024 + k);
  } else if (e < 4194304) {               // Wg0 [2048][1536], X0=[emb|ctx|lh0]
    int e2 = e - 1048576; int o = e2 / 1536, k = e2 % 1536;
    if (k < 1024) {
      if (o < 1536) v = *(const float4*)(W_ih0 + (size_t)o * 1024 + k);
    } else {
      int k2 = k - 1024;
      if (o < 1024)       v = *(const float4*)(W_hh0 + (size_t)o * 512 + k2);
      else if (o >= 1536) v = *(const float4*)(W_hh0 + (size_t)(o - 512) * 512 + k2);
    }
  } else {                                // Wg1 [2048][1024], X1=[h0|lh1]
    int e2 = e - 4194304; int o = e2 >> 10, k = e2 & 1023;
    if (k < 512) {
      if (o < 1536) v = *(const float4*)(W_ih1 + (size_t)o * 512 + k);
    } else {
      int k2 = k - 512;
      if (o < 1024)       v = *(const float4*)(W_hh1 + (size_t)o * 512 + k2);
      else if (o >= 1536) v = *(const float4*)(W_hh1 + (size_t)(o - 512) * 512 + k2);
    }
  }
  ushort4 u;
  u.x = f2bf(v.x); u.y = f2bf(v.y); u.z = f2bf(v.z); u.w = f2bf(v.w);
  *(ushort4*)(arena + e) = u;
}

// ---------- gather emb + copy lh0/lh1 into X0/X1 ----------
__global__ void gather_copy_kernel(const float* __restrict__ wdv, const int* __restrict__ ids,
                                   const float* __restrict__ lh, float* __restrict__ X0,
                                   float* __restrict__ X1) {
  int gid = blockIdx.x * 256 + threadIdx.x;  // grid 768
  int region = gid >> 16;
  int idx = gid & 65535;
  int b = idx >> 9, i = idx & 511;
  if (region == 0)
    X0[b * 1536 + i] = wdv[(size_t)b * (Vdim * Hdim) + (size_t)ids[b] * Hdim + i];
  else if (region == 1)
    X0[b * 1536 + 1024 + i] = lh[idx];
  else
    X1[b * 1024 + 512 + i] = lh[65536 + idx];
}

// ---------- thin GEMM: M=128, C[m][n] = act(sum_k X[m][k]*W[n][k] + bias[n]) ----------
// X f32 [128][ldx], W bf16 [N][K] row-major, grid = N/64, block 256 (4 waves x 32 rows)
__global__ __launch_bounds__(256)
void thin_gemm_kernel(const float* __restrict__ X, int ldx, const u16* __restrict__ W,
                      const float* __restrict__ bias, float* __restrict__ C, int ldc,
                      int K, int act) {
  int n0 = blockIdx.x * 64;
  int t = threadIdx.x, lane = t & 63, w = t >> 6;
  int fr = lane & 15, hi = lane >> 4, kof = hi * 8;
  f32x4 acc[2][4];
#pragma unroll
  for (int i = 0; i < 2; ++i)
#pragma unroll
    for (int j = 0; j < 4; ++j) acc[i][j] = (f32x4){0.f, 0.f, 0.f, 0.f};
  const float* Xr0 = X + (size_t)(w * 32 + fr) * ldx;
  const float* Xr1 = X + (size_t)(w * 32 + 16 + fr) * ldx;
#pragma unroll 2
  for (int kt = 0; kt < K; kt += 32) {
    float4 a0 = *(const float4*)(Xr0 + kt + kof);
    float4 a1 = *(const float4*)(Xr0 + kt + kof + 4);
    float4 a2 = *(const float4*)(Xr1 + kt + kof);
    float4 a3 = *(const float4*)(Xr1 + kt + kof + 4);
    bf16x8 af0 = pack_bf8(a0, a1);
    bf16x8 af1 = pack_bf8(a2, a3);
    bf16x8 bf[4];
#pragma unroll
    for (int ni = 0; ni < 4; ++ni)
      bf[ni] = *(const bf16x8*)(W + (size_t)(n0 + 16 * ni + fr) * K + kt + kof);
#pragma unroll
    for (int ni = 0; ni < 4; ++ni) {
      acc[0][ni] = __builtin_amdgcn_mfma_f32_16x16x32_bf16(af0, bf[ni], acc[0][ni], 0, 0, 0);
      acc[1][ni] = __builtin_amdgcn_mfma_f32_16x16x32_bf16(af1, bf[ni], acc[1][ni], 0, 0, 0);
    }
  }
#pragma unroll
  for (int mi = 0; mi < 2; ++mi)
#pragma unroll
    for (int ni = 0; ni < 4; ++ni) {
      int col = n0 + 16 * ni + fr;
      float vb = bias[col];
#pragma unroll
      for (int j = 0; j < 4; ++j) {
        int row = w * 32 + 16 * mi + hi * 4 + j;
        float v = acc[mi][ni][j] + vb;
        if (act) v = tanhf(v);
        C[(size_t)row * ldc + col] = v;
      }
    }
}

// ---------- fused attention energy: bf16 MFMA (m97-style) + tanh + score-dot ----------
// grid 2048 = 512 mb x 4 nb; block 256 = 4 waves (2x2 of 64x64); BK=32
__global__ __launch_bounds__(256, 2)
void attn_scores_kernel(const u16* __restrict__ enc_bf, const u16* __restrict__ Wenc,
                        const float* __restrict__ qW, const float* __restrict__ score_W,
                        float* __restrict__ scores) {
  __shared__ __align__(16) u16 As[128 * 32];
  __shared__ __align__(16) u16 Bs[128 * 32];
  int bx = blockIdx.x;
  int mb = bx >> 2, nb = bx & 3;
  int t = threadIdx.x, lane = t & 63, wid = t >> 6;
  int wm = wid >> 1, wn = wid & 1;
  int m0 = mb * 128, o0 = nb * 128;
  int fr = lane & 15, kof = (lane >> 4) * 8;
  int srow = lane >> 2;            // 0..15
  int scol = (lane & 3) * 8;       // 0,8,16,24

  f32x4 acc[4][4];
#pragma unroll
  for (int i = 0; i < 4; ++i)
#pragma unroll
    for (int j = 0; j < 4; ++j) acc[i][j] = (f32x4){0.f, 0.f, 0.f, 0.f};

  for (int kt = 0; kt < 512; kt += 32) {
#pragma unroll
    for (int p = 0; p < 2; ++p) {
      int seg = wid * 2 + p;       // 0..7 : 16 rows each
      const u16* srcA = enc_bf + (size_t)(m0 + seg * 16 + srow) * 512 + kt + scol;
      const u16* srcB = Wenc   + (size_t)(o0 + seg * 16 + srow) * 512 + kt + scol;
      gload_lds16(srcA, &As[seg * 512]);
      gload_lds16(srcB, &Bs[seg * 512]);
    }
    __syncthreads();
    bf16x8 a[4], b[4];
#pragma unroll
    for (int mi = 0; mi < 4; ++mi) a[mi] = *(const bf16x8*)&As[(wm * 64 + 16 * mi + fr) * 32 + kof];
#pragma unroll
    for (int ni = 0; ni < 4; ++ni) b[ni] = *(const bf16x8*)&Bs[(wn * 64 + 16 * ni + fr) * 32 + kof];
#pragma unroll
    for (int mi = 0; mi < 4; ++mi)
#pragma unroll
      for (int ni = 0; ni < 4; ++ni)
        acc[mi][ni] = __builtin_amdgcn_mfma_f32_16x16x32_bf16(a[mi], b[ni], acc[mi][ni], 0, 0, 0);
    __syncthreads();
  }

  int g = lane >> 4;
  int l = mb;
#pragma unroll
  for (int mi = 0; mi < 4; ++mi) {
    float rs0 = 0.f, rs1 = 0.f, rs2 = 0.f, rs3 = 0.f;
#pragma unroll
    for (int ni = 0; ni < 4; ++ni) {
      int o = o0 + wn * 64 + ni * 16 + fr;
      float sw = score_W[o];
      int brow = wm * 64 + mi * 16 + g * 4;
      rs0 += sw * fast_tanh(acc[mi][ni][0] + qW[(brow + 0) * 512 + o]);
      rs1 += sw * fast_tanh(acc[mi][ni][1] + qW[(brow + 1) * 512 + o]);
      rs2 += sw * fast_tanh(acc[mi][ni][2] + qW[(brow + 2) * 512 + o]);
      rs3 += sw * fast_tanh(acc[mi][ni][3] + qW[(brow + 3) * 512 + o]);
    }
#pragma unroll
    for (int d = 1; d < 16; d <<= 1) {
      rs0 += __shfl_xor(rs0, d);
      rs1 += __shfl_xor(rs1, d);
      rs2 += __shfl_xor(rs2, d);
      rs3 += __shfl_xor(rs3, d);
    }
    if (fr < 4) {
      float v = (fr == 0) ? rs0 : (fr == 1) ? rs1 : (fr == 2) ? rs2 : rs3;
      int b = wm * 64 + mi * 16 + g * 4 + fr;
      atomicAdd(&scores[b * Ldim + l], v);
    }
  }
}

// ---------- masked softmax over L ----------
__global__ void softmax_kernel(float* __restrict__ scores, const void* __restrict__ maskp,
                               const int* __restrict__ flag) {
  int b = blockIdx.x, t = threadIdx.x;
  bool isbyte = (*flag != 0);
  int l0 = t, l1 = t + 256;
  float s0 = scores[b * 512 + l0], s1 = scores[b * 512 + l1];
  bool m0, m1;
  if (isbyte) {
    m0 = ((const uint8_t*)maskp)[b * 512 + l0] != 0;
    m1 = ((const uint8_t*)maskp)[b * 512 + l1] != 0;
  } else {
    m0 = ((const int*)maskp)[b * 512 + l0] != 0;
    m1 = ((const int*)maskp)[b * 512 + l1] != 0;
  }
  float v0 = m0 ? -1e12f : s0;
  float v1 = m1 ? -1e12f : s1;
  __shared__ float redm[4];
  __shared__ float reds[4];
  float mx = fmaxf(v0, v1);
#pragma unroll
  for (int d = 1; d < 64; d <<= 1) mx = fmaxf(mx, __shfl_xor(mx, d));
  if ((t & 63) == 0) redm[t >> 6] = mx;
  __syncthreads();
  mx = fmaxf(fmaxf(redm[0], redm[1]), fmaxf(redm[2], redm[3]));
  float e0 = __expf(v0 - mx), e1 = __expf(v1 - mx);
  float sm = e0 + e1;
#pragma unroll
  for (int d = 1; d < 64; d <<= 1) sm += __shfl_xor(sm, d);
  if ((t & 63) == 0) reds[t >> 6] = sm;
  __syncthreads();
  sm = reds[0] + reds[1] + reds[2] + reds[3];
  float inv = 1.0f / sm;
  scores[b * 512 + l0] = e0 * inv;
  scores[b * 512 + l1] = e1 * inv;
}

// ---------- context from bf16 enc -> X0[:,512:1024] and c1[:,512:1024] ----------
__global__ void context_kernel(const u16* __restrict__ enc_bf, const float* __restrict__ aw,
                               float* __restrict__ X0, float* __restrict__ c1) {
  int b = blockIdx.x, t = threadIdx.x;  // 256 threads, 2 cols each
  __shared__ float w[512];
  w[t] = aw[b * 512 + t];
  w[t + 256] = aw[b * 512 + t + 256];
  __syncthreads();
  float a0 = 0.f, a1 = 0.f;
  for (int l = 0; l < 512; ++l) {
    float wl = w[l];
    if (wl != 0.0f) {
      uint32_t v = *(const uint32_t*)(enc_bf + ((size_t)l * 128 + b) * 512 + 2 * t);
      a0 += wl * bfhi2f(v & 0xffffu);
      a1 += wl * __uint_as_float(v & 0xffff0000u);
    }
  }
  X0[b * 1536 + 512 + 2 * t] = a0;
  X0[b * 1536 + 512 + 2 * t + 1] = a1;
  c1[b * 1024 + 512 + 2 * t] = a0;
  c1[b * 1024 + 512 + 2 * t + 1] = a1;
}

// ---------- GRU combine from fused gates g[128][2048] = [r|z|i_n|h_n] ----------
__global__ void gru_combine_kernel(const float* __restrict__ g, const float* __restrict__ hprev,
                                   float* __restrict__ hout, float* __restrict__ xdst) {
  int idx = blockIdx.x * 256 + threadIdx.x;  // 65536
  int b = idx >> 9, o = idx & 511;
  const float* gb = g + (size_t)b * 2048;
  float r = fast_sig(gb[o]);
  float z = fast_sig(gb[512 + o]);
  float n = tanhf(gb[1024 + o] + r * gb[1536 + o]);
  float h = (1.0f - z) * n + z * hprev[idx];
  hout[idx] = h;
  xdst[b * 1024 + o] = h;
}

extern "C" void kernel_launch(void* const* d_in, const int* in_sizes, int n_in,
                              void* d_out, int out_size, void* d_ws, size_t ws_size,
                              hipStream_t stream) {
  const int*   ids    = (const int*)  d_in[0];
  const float* lh     = (const float*)d_in[1];
  const float* wdv    = (const float*)d_in[2];
  const float* enc    = (const float*)d_in[3];
  const void*  mask   = d_in[4];
  const float* attn_W = (const float*)d_in[5];
  const float* attn_b = (const float*)d_in[6];
  const float* scW    = (const float*)d_in[7];
  const float* cat_W  = (const float*)d_in[8];
  const float* cat_b  = (const float*)d_in[9];
  const float* W_ih0  = (const float*)d_in[10];
  const float* W_hh0  = (const float*)d_in[11];
  const float* b_ih0  = (const float*)d_in[12];
  const float* b_hh0  = (const float*)d_in[13];
  const float* W_ih1  = (const float*)d_in[14];
  const float* W_hh1  = (const float*)d_in[15];
  const float* b_ih1  = (const float*)d_in[16];
  const float* b_hh1  = (const float*)d_in[17];

  float* out = (float*)d_out;
  float* h0  = out + 65536;
  float* h1  = out + 131072;

  float* ws     = (float*)d_ws;
  float* scores = ws;                    // 65536
  int*   flag   = (int*)(ws + 65536);    // 16
  float* qW     = ws + 65552;            // 65536
  float* X0     = ws + 131088;           // 196608 [emb|ctx|lh0]
  float* X1     = ws + 327696;           // 131072 [h0|lh1]
  float* c1     = ws + 458768;           // 131072 [h1|ctx]
  float* g0     = ws + 589840;           // 262144
  float* g1     = ws + 851984;           // 262144
  float* bias0  = ws + 1114128;          // 2048
  float* bias1  = ws + 1116176;          // 2048
  u16*   enc_bf = (u16*)(ws + 1118224);  // 33554432 bf16
  u16*   arena  = (u16*)(ws + 17895440); // 6291456 bf16

  const u16* Whid = arena;
  const u16* Wenc = arena + 262144;
  const u16* Wcat = arena + 524288;
  const u16* Wg0  = arena + 1048576;
  const u16* Wg1  = arena + 4194304;

  const float* q = lh + 65536;  // last_hidden[1]

  hipMemsetAsync(scores, 0, (65536 + 16) * sizeof(float), stream);
  detect_mask_kernel<<<256, 256, 0, stream>>>((const uint8_t*)mask, Bdim * Ldim, flag);
  prep_weights_kernel<<<6160, 256, 0, stream>>>(attn_W, cat_W, W_ih0, W_hh0, W_ih1, W_hh1,
                                                b_ih0, b_hh0, b_ih1, b_hh1,
                                                arena, bias0, bias1);
  convert_enc_kernel<<<16384, 256, 0, stream>>>(enc, enc_bf);
  gather_copy_kernel<<<768, 256, 0, stream>>>(wdv, ids, lh, X0, X1);
  // qW = q @ Whid^T + attn_b
  thin_gemm_kernel<<<8, 256, 0, stream>>>(q, 512, Whid, attn_b, qW, 512, 512, 0);
  attn_scores_kernel<<<2048, 256, 0, stream>>>(enc_bf, Wenc, qW, scW, scores);
  softmax_kernel<<<128, 256, 0, stream>>>(scores, mask, flag);
  context_kernel<<<128, 256, 0, stream>>>(enc_bf, scores, X0, c1);
  // layer 0: g0 = X0 @ Wg0^T + bias0  (fused r,z + i_n + h_n)
  thin_gemm_kernel<<<32, 256, 0, stream>>>(X0, 1536, Wg0, bias0, g0, 2048, 1536, 0);
  gru_combine_kernel<<<256, 256, 0, stream>>>(g0, lh, h0, X1);
  // layer 1
  thin_gemm_kernel<<<32, 256, 0, stream>>>(X1, 1024, Wg1, bias1, g1, 2048, 1024, 0);
  gru_combine_kernel<<<256, 256, 0, stream>>>(g1, q, h1, c1);
  // output = tanh(c1 @ Wcat^T + cat_b)
  thin_gemm_kernel<<<8, 256, 0, stream>>>(c1, 1024, Wcat, cat_b, out, 512, 1024, 1);
}

// Round 3
// 345.749 us; speedup vs baseline: 1.3266x; 1.2385x over previous
//
#include <hip/hip_runtime.h>
#include <stdint.h>

#define Hdim 512
#define Bdim 128
#define Ldim 512
#define Vdim 2048

typedef unsigned short u16;
using f32x4  = float  __attribute__((ext_vector_type(4)));
using bf16x8 = __bf16 __attribute__((ext_vector_type(8)));

__device__ inline u16 f2bf(float x) {
  uint32_t u = __float_as_uint(x);
  u += 0x7fffu + ((u >> 16) & 1u);   // RNE
  return (u16)(u >> 16);
}
__device__ inline float bfhi2f(uint32_t hi16) { return __uint_as_float(hi16 << 16); }
__device__ inline float fast_tanh(float x) {
  return 1.0f - 2.0f / (__expf(2.0f * x) + 1.0f);
}
__device__ inline float fast_sig(float x) { return 1.0f / (1.0f + __expf(-x)); }

__device__ inline void gload_lds16(const u16* g, u16* l) {
  auto gp = (const __attribute__((address_space(1))) uint32_t*)(uintptr_t)g;
  auto lp = (__attribute__((address_space(3))) uint32_t*)(uintptr_t)l;
  __builtin_amdgcn_global_load_lds(gp, lp, 16, 0, 0);
}

// ---------- mask dtype detection (single block, self-contained init) ----------
__global__ void detect_mask_kernel(const uint8_t* __restrict__ m, int nbytes, int* flag) {
  __shared__ int sf;
  int t = threadIdx.x;  // 1024
  if (t == 0) sf = 0;
  __syncthreads();
  int found = 0;
  for (int i = t * 4; i < nbytes; i += 1024 * 4) {
    uint32_t v = *(const uint32_t*)(m + i);
    if (v & 0xffffff00u) found = 1;   // nonzero byte at pos%4!=0 => byte mask
  }
  if (found) sf = 1;
  __syncthreads();
  if (t == 0) *flag = sf;
}

// ---------- enc f32 -> bf16 ----------
__global__ void convert_enc_kernel(const float* __restrict__ src, u16* __restrict__ dst) {
  size_t i = ((size_t)blockIdx.x * 256 + threadIdx.x) * 8;  // 33554432 total
  float4 a = *(const float4*)(src + i);
  float4 b = *(const float4*)(src + i + 4);
  ushort4 u0, u1;
  u0.x = f2bf(a.x); u0.y = f2bf(a.y); u0.z = f2bf(a.z); u0.w = f2bf(a.w);
  u1.x = f2bf(b.x); u1.y = f2bf(b.y); u1.z = f2bf(b.z); u1.w = f2bf(b.w);
  *(ushort4*)(dst + i) = u0;
  *(ushort4*)(dst + i + 4) = u1;
}

// ---------- weight prep: bf16 arena + fused GRU layouts + fused bias ----------
// arena: Whid@0 (512x512), Wenc@262144 (512x512), Wcat@524288 (512x1024),
//        Wg0@1048576 (2048x1536), Wg1@4194304 (2048x1024)   total 6291456
__global__ void prep_weights_kernel(const float* __restrict__ attn_W, const float* __restrict__ cat_W,
                                    const float* __restrict__ W_ih0, const float* __restrict__ W_hh0,
                                    const float* __restrict__ W_ih1, const float* __restrict__ W_hh1,
                                    const float* __restrict__ b_ih0, const float* __restrict__ b_hh0,
                                    const float* __restrict__ b_ih1, const float* __restrict__ b_hh1,
                                    u16* __restrict__ arena, float* __restrict__ bias0,
                                    float* __restrict__ bias1) {
  int gid = blockIdx.x * 256 + threadIdx.x;
  if (blockIdx.x >= 6144) {  // bias blocks
    int r = gid - 6144 * 256;
    if (r < 2048) {
      int o = r;
      bias0[o] = (o < 1024) ? b_ih0[o] + b_hh0[o] : (o < 1536 ? b_ih0[o] : b_hh0[o - 512]);
    } else if (r < 4096) {
      int o = r - 2048;
      bias1[o] = (o < 1024) ? b_ih1[o] + b_hh1[o] : (o < 1536 ? b_ih1[o] : b_hh1[o - 512]);
    }
    return;
  }
  int e = gid * 4;
  float4 v = {0.f, 0.f, 0.f, 0.f};
  if (e < 262144) {                       // Whid = attn_W[:, :512]
    int o = e >> 9, k = e & 511;
    v = *(const float4*)(attn_W + (size_t)o * 1024 + k);
  } else if (e < 524288) {                // Wenc = attn_W[:, 512:]
    int e2 = e - 262144; int o = e2 >> 9, k = e2 & 511;
    v = *(const float4*)(attn_W + (size_t)o * 1024 + 512 + k);
  } else if (e < 1048576) {               // Wcat
    int e2 = e - 524288; int o = e2 >> 10, k = e2 & 1023;
    v = *(const float4*)(cat_W + (size_t)o * 1024 + k);
  } else if (e < 4194304) {               // Wg0 [2048][1536], X0=[emb|ctx|lh0]
    int e2 = e - 1048576; int o = e2 / 1536, k = e2 % 1536;
    if (k < 1024) {
      if (o < 1536) v = *(const float4*)(W_ih0 + (size_t)o * 1024 + k);
    } else {
      int k2 = k - 1024;
      if (o < 1024)       v = *(const float4*)(W_hh0 + (size_t)o * 512 + k2);
      else if (o >= 1536) v = *(const float4*)(W_hh0 + (size_t)(o - 512) * 512 + k2);
    }
  } else {                                // Wg1 [2048][1024], X1=[h0|lh1]
    int e2 = e - 4194304; int o = e2 >> 10, k = e2 & 1023;
    if (k < 512) {
      if (o < 1536) v = *(const float4*)(W_ih1 + (size_t)o * 512 + k);
    } else {
      int k2 = k - 512;
      if (o < 1024)       v = *(const float4*)(W_hh1 + (size_t)o * 512 + k2);
      else if (o >= 1536) v = *(const float4*)(W_hh1 + (size_t)(o - 512) * 512 + k2);
    }
  }
  ushort4 u;
  u.x = f2bf(v.x); u.y = f2bf(v.y); u.z = f2bf(v.z); u.w = f2bf(v.w);
  *(ushort4*)(arena + e) = u;
}

// ---------- gather emb (bf16) + copy lh0/lh1 (bf16) into X0bf/X1bf ----------
__global__ void gather_copy_kernel(const float* __restrict__ wdv, const int* __restrict__ ids,
                                   const float* __restrict__ lh, u16* __restrict__ X0bf,
                                   u16* __restrict__ X1bf) {
  int gid = blockIdx.x * 256 + threadIdx.x;  // grid 768
  int region = gid >> 16;
  int idx = gid & 65535;
  int b = idx >> 9, i = idx & 511;
  if (region == 0)
    X0bf[b * 1536 + i] = f2bf(wdv[(size_t)b * (Vdim * Hdim) + (size_t)ids[b] * Hdim + i]);
  else if (region == 1)
    X0bf[b * 1536 + 1024 + i] = f2bf(lh[idx]);
  else
    X1bf[b * 1024 + 512 + i] = f2bf(lh[65536 + idx]);
}

// ---------- thin GEMM (bf16 X): M=128, C[m][n] = act(sum_k X[m][k]*W[n][k] + bias[n]) ----------
// X bf16 [128][ldx], W bf16 [N][K] row-major, grid = N/64, block 256 (4 waves x 32 rows)
__global__ __launch_bounds__(256)
void thin_gemm_bf16(const u16* __restrict__ X, int ldx, const u16* __restrict__ W,
                    const float* __restrict__ bias, float* __restrict__ C, int ldc,
                    int K, int act) {
  int n0 = blockIdx.x * 64;
  int t = threadIdx.x, lane = t & 63, w = t >> 6;
  int fr = lane & 15, hi = lane >> 4, kof = hi * 8;
  f32x4 acc[2][4];
#pragma unroll
  for (int i = 0; i < 2; ++i)
#pragma unroll
    for (int j = 0; j < 4; ++j) acc[i][j] = (f32x4){0.f, 0.f, 0.f, 0.f};
  const u16* Xr0 = X + (size_t)(w * 32 + fr) * ldx;
  const u16* Xr1 = Xr0 + (size_t)16 * ldx;
#pragma unroll 4
  for (int kt = 0; kt < K; kt += 32) {
    bf16x8 a0 = *(const bf16x8*)(Xr0 + kt + kof);
    bf16x8 a1 = *(const bf16x8*)(Xr1 + kt + kof);
    bf16x8 bv[4];
#pragma unroll
    for (int ni = 0; ni < 4; ++ni)
      bv[ni] = *(const bf16x8*)(W + (size_t)(n0 + 16 * ni + fr) * K + kt + kof);
#pragma unroll
    for (int ni = 0; ni < 4; ++ni) {
      acc[0][ni] = __builtin_amdgcn_mfma_f32_16x16x32_bf16(a0, bv[ni], acc[0][ni], 0, 0, 0);
      acc[1][ni] = __builtin_amdgcn_mfma_f32_16x16x32_bf16(a1, bv[ni], acc[1][ni], 0, 0, 0);
    }
  }
#pragma unroll
  for (int mi = 0; mi < 2; ++mi)
#pragma unroll
    for (int ni = 0; ni < 4; ++ni) {
      int col = n0 + 16 * ni + fr;
      float vb = bias[col];
#pragma unroll
      for (int j = 0; j < 4; ++j) {
        int row = w * 32 + 16 * mi + hi * 4 + j;
        float v = acc[mi][ni][j] + vb;
        if (act) v = tanhf(v);
        C[(size_t)row * ldc + col] = v;
      }
    }
}

// ---------- fused attention energy: bf16 MFMA + tanh + score-dot -> partials (no atomics) ----------
// grid 2048 = 512 mb x 4 nb; block 256 = 4 waves (2x2 of 64x64); BK=32
__global__ __launch_bounds__(256, 2)
void attn_scores_kernel(const u16* __restrict__ enc_bf, const u16* __restrict__ Wenc,
                        const float* __restrict__ qW, const float* __restrict__ score_W,
                        float* __restrict__ scores_p) {
  __shared__ __align__(16) u16 As[128 * 32];
  __shared__ __align__(16) u16 Bs[128 * 32];
  __shared__ float part[4][4][16];
  int bx = blockIdx.x;
  int mb = bx >> 2, nb = bx & 3;
  int t = threadIdx.x, lane = t & 63, wid = t >> 6;
  int wm = wid >> 1, wn = wid & 1;
  int m0 = mb * 128, o0 = nb * 128;
  int fr = lane & 15, kof = (lane >> 4) * 8;
  int srow = lane >> 2;            // 0..15
  int scol = (lane & 3) * 8;       // 0,8,16,24

  f32x4 acc[4][4];
#pragma unroll
  for (int i = 0; i < 4; ++i)
#pragma unroll
    for (int j = 0; j < 4; ++j) acc[i][j] = (f32x4){0.f, 0.f, 0.f, 0.f};

  for (int kt = 0; kt < 512; kt += 32) {
#pragma unroll
    for (int p = 0; p < 2; ++p) {
      int seg = wid * 2 + p;       // 0..7 : 16 rows each
      const u16* srcA = enc_bf + (size_t)(m0 + seg * 16 + srow) * 512 + kt + scol;
      const u16* srcB = Wenc   + (size_t)(o0 + seg * 16 + srow) * 512 + kt + scol;
      gload_lds16(srcA, &As[seg * 512]);
      gload_lds16(srcB, &Bs[seg * 512]);
    }
    __syncthreads();
    bf16x8 a[4], b[4];
#pragma unroll
    for (int mi = 0; mi < 4; ++mi) a[mi] = *(const bf16x8*)&As[(wm * 64 + 16 * mi + fr) * 32 + kof];
#pragma unroll
    for (int ni = 0; ni < 4; ++ni) b[ni] = *(const bf16x8*)&Bs[(wn * 64 + 16 * ni + fr) * 32 + kof];
#pragma unroll
    for (int mi = 0; mi < 4; ++mi)
#pragma unroll
      for (int ni = 0; ni < 4; ++ni)
        acc[mi][ni] = __builtin_amdgcn_mfma_f32_16x16x32_bf16(a[mi], b[ni], acc[mi][ni], 0, 0, 0);
    __syncthreads();
  }

  int g = lane >> 4;
  int l = mb;
#pragma unroll
  for (int mi = 0; mi < 4; ++mi) {
    float rs0 = 0.f, rs1 = 0.f, rs2 = 0.f, rs3 = 0.f;
#pragma unroll
    for (int ni = 0; ni < 4; ++ni) {
      int o = o0 + wn * 64 + ni * 16 + fr;
      float sw = score_W[o];
      int brow = wm * 64 + mi * 16 + g * 4;
      rs0 += sw * fast_tanh(acc[mi][ni][0] + qW[(brow + 0) * 512 + o]);
      rs1 += sw * fast_tanh(acc[mi][ni][1] + qW[(brow + 1) * 512 + o]);
      rs2 += sw * fast_tanh(acc[mi][ni][2] + qW[(brow + 2) * 512 + o]);
      rs3 += sw * fast_tanh(acc[mi][ni][3] + qW[(brow + 3) * 512 + o]);
    }
#pragma unroll
    for (int d = 1; d < 16; d <<= 1) {
      rs0 += __shfl_xor(rs0, d);
      rs1 += __shfl_xor(rs1, d);
      rs2 += __shfl_xor(rs2, d);
      rs3 += __shfl_xor(rs3, d);
    }
    if (fr < 4) {
      float v = (fr == 0) ? rs0 : (fr == 1) ? rs1 : (fr == 2) ? rs2 : rs3;
      part[wid][mi][g * 4 + fr] = v;
    }
  }
  __syncthreads();
  // combine wn halves: waves 0 and 2 (wn==0) each cover their wm's 64 rows
  if ((wid & 1) == 0) {
    int mi = lane >> 4, s = lane & 15;
    float sum = part[wid][mi][s] + part[wid + 1][mi][s];
    int b = wm * 64 + mi * 16 + s;
    scores_p[((size_t)nb * 128 + b) * 512 + l] = sum;
  }
}

// ---------- fused mask + softmax + context -> X0bf[:,512:1024], c1bf[:,512:1024] ----------
__global__ void softctx_kernel(const float* __restrict__ sp, const void* __restrict__ maskp,
                               const int* __restrict__ flag, const u16* __restrict__ enc_bf,
                               u16* __restrict__ X0bf, u16* __restrict__ c1bf) {
  int b = blockIdx.x, t = threadIdx.x;  // 256 threads
  int l0 = t, l1 = t + 256;
  float s0 = sp[(size_t)(0 * 128 + b) * 512 + l0] + sp[(size_t)(1 * 128 + b) * 512 + l0]
           + sp[(size_t)(2 * 128 + b) * 512 + l0] + sp[(size_t)(3 * 128 + b) * 512 + l0];
  float s1 = sp[(size_t)(0 * 128 + b) * 512 + l1] + sp[(size_t)(1 * 128 + b) * 512 + l1]
           + sp[(size_t)(2 * 128 + b) * 512 + l1] + sp[(size_t)(3 * 128 + b) * 512 + l1];
  bool isbyte = (*flag != 0);
  bool m0, m1;
  if (isbyte) {
    m0 = ((const uint8_t*)maskp)[b * 512 + l0] != 0;
    m1 = ((const uint8_t*)maskp)[b * 512 + l1] != 0;
  } else {
    m0 = ((const int*)maskp)[b * 512 + l0] != 0;
    m1 = ((const int*)maskp)[b * 512 + l1] != 0;
  }
  float v0 = m0 ? -1e12f : s0;
  float v1 = m1 ? -1e12f : s1;
  __shared__ float redm[4];
  __shared__ float reds[4];
  __shared__ float wgt[512];
  float mx = fmaxf(v0, v1);
#pragma unroll
  for (int d = 1; d < 64; d <<= 1) mx = fmaxf(mx, __shfl_xor(mx, d));
  if ((t & 63) == 0) redm[t >> 6] = mx;
  __syncthreads();
  mx = fmaxf(fmaxf(redm[0], redm[1]), fmaxf(redm[2], redm[3]));
  float e0 = __expf(v0 - mx), e1 = __expf(v1 - mx);
  float sm = e0 + e1;
#pragma unroll
  for (int d = 1; d < 64; d <<= 1) sm += __shfl_xor(sm, d);
  if ((t & 63) == 0) reds[t >> 6] = sm;
  __syncthreads();
  sm = reds[0] + reds[1] + reds[2] + reds[3];
  float inv = 1.0f / sm;
  wgt[l0] = e0 * inv;
  wgt[l1] = e1 * inv;
  __syncthreads();
  float a0 = 0.f, a1 = 0.f;
  for (int l = 0; l < 512; ++l) {
    float wl = wgt[l];
    if (wl != 0.0f) {
      uint32_t v = *(const uint32_t*)(enc_bf + ((size_t)l * 128 + b) * 512 + 2 * t);
      a0 += wl * bfhi2f(v & 0xffffu);
      a1 += wl * __uint_as_float(v & 0xffff0000u);
    }
  }
  uint32_t packed = (uint32_t)f2bf(a0) | ((uint32_t)f2bf(a1) << 16);
  *(uint32_t*)(X0bf + b * 1536 + 512 + 2 * t) = packed;
  *(uint32_t*)(c1bf + b * 1024 + 512 + 2 * t) = packed;
}

// ---------- GRU combine from fused gates g[128][2048] = [r|z|i_n|h_n] ----------
__global__ void gru_combine_kernel(const float* __restrict__ g, const float* __restrict__ hprev,
                                   float* __restrict__ hout, u16* __restrict__ xdst) {
  int idx = blockIdx.x * 256 + threadIdx.x;  // 65536
  int b = idx >> 9, o = idx & 511;
  const float* gb = g + (size_t)b * 2048;
  float r = fast_sig(gb[o]);
  float z = fast_sig(gb[512 + o]);
  float n = tanhf(gb[1024 + o] + r * gb[1536 + o]);
  float h = (1.0f - z) * n + z * hprev[idx];
  hout[idx] = h;
  xdst[b * 1024 + o] = f2bf(h);
}

extern "C" void kernel_launch(void* const* d_in, const int* in_sizes, int n_in,
                              void* d_out, int out_size, void* d_ws, size_t ws_size,
                              hipStream_t stream) {
  const int*   ids    = (const int*)  d_in[0];
  const float* lh     = (const float*)d_in[1];
  const float* wdv    = (const float*)d_in[2];
  const float* enc    = (const float*)d_in[3];
  const void*  mask   = d_in[4];
  const float* attn_W = (const float*)d_in[5];
  const float* attn_b = (const float*)d_in[6];
  const float* scW    = (const float*)d_in[7];
  const float* cat_W  = (const float*)d_in[8];
  const float* cat_b  = (const float*)d_in[9];
  const float* W_ih0  = (const float*)d_in[10];
  const float* W_hh0  = (const float*)d_in[11];
  const float* b_ih0  = (const float*)d_in[12];
  const float* b_hh0  = (const float*)d_in[13];
  const float* W_ih1  = (const float*)d_in[14];
  const float* W_hh1  = (const float*)d_in[15];
  const float* b_ih1  = (const float*)d_in[16];
  const float* b_hh1  = (const float*)d_in[17];

  float* out = (float*)d_out;
  float* h0  = out + 65536;
  float* h1  = out + 131072;

  float* ws       = (float*)d_ws;
  float* scores_p = ws;                      // 262144  [4][128][512]
  float* qW       = ws + 262144;             // 65536
  float* g0       = ws + 327680;             // 262144
  float* g1       = ws + 589824;             // 262144
  float* bias0    = ws + 851968;             // 2048
  float* bias1    = ws + 854016;             // 2048
  int*   flag     = (int*)(ws + 856064);     // 16
  u16*   arena    = (u16*)(ws + 856080);     // 6291456 u16
  u16*   enc_bf   = (u16*)(ws + 4001808);    // 33554432 u16
  u16*   X0bf     = (u16*)(ws + 20779024);   // 196608 u16 [emb|ctx|lh0]
  u16*   X1bf     = (u16*)(ws + 20877328);   // 131072 u16 [h0|lh1]
  u16*   c1bf     = (u16*)(ws + 20942864);   // 131072 u16 [h1|ctx]

  const u16* Whid = arena;
  const u16* Wenc = arena + 262144;
  const u16* Wcat = arena + 524288;
  const u16* Wg0  = arena + 1048576;
  const u16* Wg1  = arena + 4194304;

  const float* q = lh + 65536;  // last_hidden[1]

  detect_mask_kernel<<<1, 1024, 0, stream>>>((const uint8_t*)mask, Bdim * Ldim, flag);
  prep_weights_kernel<<<6160, 256, 0, stream>>>(attn_W, cat_W, W_ih0, W_hh0, W_ih1, W_hh1,
                                                b_ih0, b_hh0, b_ih1, b_hh1,
                                                arena, bias0, bias1);
  convert_enc_kernel<<<16384, 256, 0, stream>>>(enc, enc_bf);
  gather_copy_kernel<<<768, 256, 0, stream>>>(wdv, ids, lh, X0bf, X1bf);
  // qW = q @ Whid^T + attn_b   (q as bf16 lives in X1bf[:,512:1024])
  thin_gemm_bf16<<<8, 256, 0, stream>>>(X1bf + 512, 1024, Whid, attn_b, qW, 512, 512, 0);
  attn_scores_kernel<<<2048, 256, 0, stream>>>(enc_bf, Wenc, qW, scW, scores_p);
  softctx_kernel<<<128, 256, 0, stream>>>(scores_p, mask, flag, enc_bf, X0bf, c1bf);
  // layer 0: g0 = X0 @ Wg0^T + bias0  (fused r,z + i_n + h_n)
  thin_gemm_bf16<<<32, 256, 0, stream>>>(X0bf, 1536, Wg0, bias0, g0, 2048, 1536, 0);
  gru_combine_kernel<<<256, 256, 0, stream>>>(g0, lh, h0, X1bf);
  // layer 1
  thin_gemm_bf16<<<32, 256, 0, stream>>>(X1bf, 1024, Wg1, bias1, g1, 2048, 1024, 0);
  gru_combine_kernel<<<256, 256, 0, stream>>>(g1, q, h1, c1bf);
  // output = tanh(c1 @ Wcat^T + cat_b)
  thin_gemm_bf16<<<8, 256, 0, stream>>>(c1bf, 1024, Wcat, cat_b, out, 512, 1024, 1);
}

// Round 4
// 210.278 us; speedup vs baseline: 2.1813x; 1.6442x over previous
//
#include <hip/hip_runtime.h>
#include <stdint.h>

#define Hdim 512
#define Bdim 128
#define Ldim 512
#define Vdim 2048

typedef unsigned short u16;
using f32x4  = float  __attribute__((ext_vector_type(4)));
using bf16x8 = __bf16 __attribute__((ext_vector_type(8)));

__device__ inline u16 f2bf(float x) {
  uint32_t u = __float_as_uint(x);
  u += 0x7fffu + ((u >> 16) & 1u);   // RNE
  return (u16)(u >> 16);
}
__device__ inline float bfhi2f(uint32_t hi16) { return __uint_as_float(hi16 << 16); }
__device__ inline float fast_tanh(float x) {
  return 1.0f - 2.0f / (__expf(2.0f * x) + 1.0f);
}
__device__ inline float fast_sig(float x) { return 1.0f / (1.0f + __expf(-x)); }

__device__ inline void gload_lds16(const u16* g, u16* l) {
  auto gp = (const __attribute__((address_space(1))) uint32_t*)(uintptr_t)g;
  auto lp = (__attribute__((address_space(3))) uint32_t*)(uintptr_t)l;
  __builtin_amdgcn_global_load_lds(gp, lp, 16, 0, 0);
}

// =======================================================================
// prep_all: convert enc->bf16 | build bf16 weight arena (gate-interleaved
// GRU layouts) | fused biases | emb gather + lh copies | mask-dtype detect
// =======================================================================
__global__ void prep_all_kernel(const float* __restrict__ enc, u16* __restrict__ enc_bf,
                                const float* __restrict__ attn_W, const float* __restrict__ cat_W,
                                const float* __restrict__ W_ih0, const float* __restrict__ W_hh0,
                                const float* __restrict__ W_ih1, const float* __restrict__ W_hh1,
                                const float* __restrict__ b_ih0, const float* __restrict__ b_hh0,
                                const float* __restrict__ b_ih1, const float* __restrict__ b_hh1,
                                u16* __restrict__ arena, float* __restrict__ biasg0,
                                float* __restrict__ biasg1,
                                const float* __restrict__ wdv, const int* __restrict__ ids,
                                const float* __restrict__ lh, u16* __restrict__ X0bf,
                                u16* __restrict__ X1bf,
                                const uint8_t* __restrict__ maskb, int* __restrict__ flag) {
  int blk = blockIdx.x, t = threadIdx.x;
  if (blk < 16384) {                       // R0: enc f32 -> bf16, 8 elems/thread
    size_t i = ((size_t)blk * 256 + t) * 8;
    float4 a = *(const float4*)(enc + i);
    float4 b = *(const float4*)(enc + i + 4);
    ushort4 u0, u1;
    u0.x = f2bf(a.x); u0.y = f2bf(a.y); u0.z = f2bf(a.z); u0.w = f2bf(a.w);
    u1.x = f2bf(b.x); u1.y = f2bf(b.y); u1.z = f2bf(b.z); u1.w = f2bf(b.w);
    *(ushort4*)(enc_bf + i) = u0;
    *(ushort4*)(enc_bf + i + 4) = u1;
    return;
  }
  if (blk < 22528) {                       // R1: weight arena, 4 elems/thread
    int e = ((blk - 16384) * 256 + t) * 4;
    float4 v = {0.f, 0.f, 0.f, 0.f};
    if (e < 262144) {                      // Whid = attn_W[:, :512]
      int o = e >> 9, k = e & 511;
      v = *(const float4*)(attn_W + (size_t)o * 1024 + k);
    } else if (e < 524288) {               // Wenc = attn_W[:, 512:]
      int e2 = e - 262144; int o = e2 >> 9, k = e2 & 511;
      v = *(const float4*)(attn_W + (size_t)o * 1024 + 512 + k);
    } else if (e < 1048576) {              // Wcat
      int e2 = e - 524288; int o = e2 >> 10, k = e2 & 1023;
      v = *(const float4*)(cat_W + (size_t)o * 1024 + k);
    } else if (e < 4194304) {              // Wg0p [2048=4o+g][1536]
      int e2 = e - 1048576; int row = e2 / 1536, k = e2 % 1536;
      int o = row >> 2, gt = row & 3;
      if (gt == 0)      v = (k < 1024) ? *(const float4*)(W_ih0 + (size_t)o * 1024 + k)
                                       : *(const float4*)(W_hh0 + (size_t)o * 512 + k - 1024);
      else if (gt == 1) v = (k < 1024) ? *(const float4*)(W_ih0 + (size_t)(512 + o) * 1024 + k)
                                       : *(const float4*)(W_hh0 + (size_t)(512 + o) * 512 + k - 1024);
      else if (gt == 2) { if (k < 1024) v = *(const float4*)(W_ih0 + (size_t)(1024 + o) * 1024 + k); }
      else              { if (k >= 1024) v = *(const float4*)(W_hh0 + (size_t)(1024 + o) * 512 + k - 1024); }
    } else {                               // Wg1p [2048=4o+g][1024]
      int e2 = e - 4194304; int row = e2 >> 10, k = e2 & 1023;
      int o = row >> 2, gt = row & 3;
      if (gt == 0)      v = (k < 512) ? *(const float4*)(W_ih1 + (size_t)o * 512 + k)
                                      : *(const float4*)(W_hh1 + (size_t)o * 512 + k - 512);
      else if (gt == 1) v = (k < 512) ? *(const float4*)(W_ih1 + (size_t)(512 + o) * 512 + k)
                                      : *(const float4*)(W_hh1 + (size_t)(512 + o) * 512 + k - 512);
      else if (gt == 2) { if (k < 512) v = *(const float4*)(W_ih1 + (size_t)(1024 + o) * 512 + k); }
      else              { if (k >= 512) v = *(const float4*)(W_hh1 + (size_t)(1024 + o) * 512 + k - 512); }
    }
    ushort4 u;
    u.x = f2bf(v.x); u.y = f2bf(v.y); u.z = f2bf(v.z); u.w = f2bf(v.w);
    *(ushort4*)(arena + e) = u;
    return;
  }
  if (blk < 22544) {                       // R2: fused gate biases (4o+g layout)
    int idx = (blk - 22528) * 256 + t;     // [0,4096)
    int layer = idx >> 11, r = idx & 2047;
    int o = r >> 2, gt = r & 3;
    float v;
    if (layer == 0) {
      v = (gt == 0) ? b_ih0[o] + b_hh0[o]
        : (gt == 1) ? b_ih0[512 + o] + b_hh0[512 + o]
        : (gt == 2) ? b_ih0[1024 + o] : b_hh0[1024 + o];
      biasg0[r] = v;
    } else {
      v = (gt == 0) ? b_ih1[o] + b_hh1[o]
        : (gt == 1) ? b_ih1[512 + o] + b_hh1[512 + o]
        : (gt == 2) ? b_ih1[1024 + o] : b_hh1[1024 + o];
      biasg1[r] = v;
    }
    return;
  }
  if (blk < 23312) {                       // R3: gather emb + lh copies (bf16)
    int gid = (blk - 22544) * 256 + t;
    int region = gid >> 16, idx = gid & 65535;
    int b = idx >> 9, i = idx & 511;
    if (region == 0)
      X0bf[b * 1536 + i] = f2bf(wdv[(size_t)b * (Vdim * Hdim) + (size_t)ids[b] * Hdim + i]);
    else if (region == 1)
      X0bf[b * 1536 + 1024 + i] = f2bf(lh[idx]);          // lh[0]
    else
      X1bf[b * 1024 + 512 + i] = f2bf(lh[65536 + idx]);   // lh[1] = q
    return;
  }
  {                                        // R4: mask dtype detect (1 block)
    __shared__ int sf;
    if (t == 0) sf = 0;
    __syncthreads();
    int found = 0;
    for (int i = t * 4; i < Bdim * Ldim; i += 256 * 4) {
      uint32_t v = *(const uint32_t*)(maskb + i);
      if (v & 0xffffff00u) found = 1;      // nonzero byte at pos%4!=0 => byte mask
    }
    if (found) sf = 1;
    __syncthreads();
    if (t == 0) *flag = sf;
  }
}

// =======================================================================
// thin GEMM, N-tile 32: C[m][n] = act(sum_k X[m][k]*W[n][k] + bias[n])
// X bf16 [128][ldx], W bf16 [N][K], grid N/32, block 256 (4 waves x 32 rows)
// =======================================================================
__global__ __launch_bounds__(256)
void thin_gemm32(const u16* __restrict__ X, int ldx, const u16* __restrict__ W,
                 const float* __restrict__ bias, float* __restrict__ C, int ldc,
                 int K, int act) {
  int n0 = blockIdx.x * 32;
  int t = threadIdx.x, lane = t & 63, w = t >> 6;
  int fr = lane & 15, g = lane >> 4, kof = g * 8;
  f32x4 acc[2][2];
#pragma unroll
  for (int i = 0; i < 2; ++i)
#pragma unroll
    for (int j = 0; j < 2; ++j) acc[i][j] = (f32x4){0.f, 0.f, 0.f, 0.f};
  const u16* Xr0 = X + (size_t)(w * 32 + fr) * ldx;
  const u16* Xr1 = Xr0 + (size_t)16 * ldx;
  const u16* Wr0 = W + (size_t)(n0 + fr) * K;
  const u16* Wr1 = W + (size_t)(n0 + 16 + fr) * K;
#pragma unroll 4
  for (int kt = 0; kt < K; kt += 32) {
    bf16x8 a0 = *(const bf16x8*)(Xr0 + kt + kof);
    bf16x8 a1 = *(const bf16x8*)(Xr1 + kt + kof);
    bf16x8 b0 = *(const bf16x8*)(Wr0 + kt + kof);
    bf16x8 b1 = *(const bf16x8*)(Wr1 + kt + kof);
    acc[0][0] = __builtin_amdgcn_mfma_f32_16x16x32_bf16(a0, b0, acc[0][0], 0, 0, 0);
    acc[0][1] = __builtin_amdgcn_mfma_f32_16x16x32_bf16(a0, b1, acc[0][1], 0, 0, 0);
    acc[1][0] = __builtin_amdgcn_mfma_f32_16x16x32_bf16(a1, b0, acc[1][0], 0, 0, 0);
    acc[1][1] = __builtin_amdgcn_mfma_f32_16x16x32_bf16(a1, b1, acc[1][1], 0, 0, 0);
  }
#pragma unroll
  for (int mi = 0; mi < 2; ++mi)
#pragma unroll
    for (int ni = 0; ni < 2; ++ni) {
      int col = n0 + ni * 16 + fr;
      float vb = bias[col];
#pragma unroll
      for (int j = 0; j < 4; ++j) {
        int row = w * 32 + 16 * mi + g * 4 + j;
        float v = acc[mi][ni][j] + vb;
        if (act) v = tanhf(v);
        C[(size_t)row * ldc + col] = v;
      }
    }
}

// =======================================================================
// attention energy: one block per l. 8 waves, full H=512 o-range in block.
// energy[b][o] = enc[l,b,:] @ Wenc[o,:] ; score = sum_o sW[o]*tanh(e+qW[b][o])
// double-buffered global_load_lds staging, K-step 32.
// =======================================================================
__global__ __launch_bounds__(512)
void attn_scores_kernel(const u16* __restrict__ enc_bf, const u16* __restrict__ Wenc,
                        const float* __restrict__ qW, const float* __restrict__ score_W,
                        float* __restrict__ scores) {
  __shared__ __align__(16) u16 As[2][4096];    // 128 rows x 32 k
  __shared__ __align__(16) u16 Bs[2][16384];   // 512 rows x 32 k
  __shared__ float part[8][128];
  int mb = blockIdx.x;                          // = l
  int t = threadIdx.x, lane = t & 63, wid = t >> 6;
  int fr = lane & 15, g = lane >> 4, kof = g * 8;
  int m0 = mb * 128;                            // enc_flat row base (l*128 + b)
  int lrow = lane >> 2, lseg = (lane & 3) * 8;  // staging: 4 lanes per row

  f32x4 acc[8][4];
#pragma unroll
  for (int i = 0; i < 8; ++i)
#pragma unroll
    for (int j = 0; j < 4; ++j) acc[i][j] = (f32x4){0.f, 0.f, 0.f, 0.f};

  // ---- stage K-tile kt into buffer sel ----
  auto STAGE = [&](int kt, int sel) {
    {
      int row = wid * 16 + lrow;
      gload_lds16(enc_bf + (size_t)(m0 + row) * 512 + kt + lseg, &As[sel][wid * 512]);
    }
#pragma unroll
    for (int i = 0; i < 4; ++i) {
      int ch = wid * 4 + i;
      int row = ch * 16 + lrow;
      gload_lds16(Wenc + (size_t)row * 512 + kt + lseg, &Bs[sel][ch * 512]);
    }
  };

  STAGE(0, 0);
  __syncthreads();
#pragma unroll 1
  for (int step = 0; step < 16; ++step) {
    int sel = step & 1;
    if (step < 15) STAGE((step + 1) * 32, sel ^ 1);
    bf16x8 a[8], b[4];
#pragma unroll
    for (int mi = 0; mi < 8; ++mi) a[mi] = *(const bf16x8*)&As[sel][(mi * 16 + fr) * 32 + kof];
#pragma unroll
    for (int ni = 0; ni < 4; ++ni) b[ni] = *(const bf16x8*)&Bs[sel][(wid * 64 + ni * 16 + fr) * 32 + kof];
#pragma unroll
    for (int mi = 0; mi < 8; ++mi)
#pragma unroll
      for (int ni = 0; ni < 4; ++ni)
        acc[mi][ni] = __builtin_amdgcn_mfma_f32_16x16x32_bf16(a[mi], b[ni], acc[mi][ni], 0, 0, 0);
    __syncthreads();
  }

  // ---- epilogue: +qW, tanh, *score_W, reduce over o ----
#pragma unroll
  for (int mi = 0; mi < 8; ++mi) {
    float rs0 = 0.f, rs1 = 0.f, rs2 = 0.f, rs3 = 0.f;
#pragma unroll
    for (int ni = 0; ni < 4; ++ni) {
      int o = wid * 64 + ni * 16 + fr;
      float sw = score_W[o];
      int brow = mi * 16 + g * 4;
      rs0 += sw * fast_tanh(acc[mi][ni][0] + qW[(brow + 0) * 512 + o]);
      rs1 += sw * fast_tanh(acc[mi][ni][1] + qW[(brow + 1) * 512 + o]);
      rs2 += sw * fast_tanh(acc[mi][ni][2] + qW[(brow + 2) * 512 + o]);
      rs3 += sw * fast_tanh(acc[mi][ni][3] + qW[(brow + 3) * 512 + o]);
    }
#pragma unroll
    for (int d = 1; d < 16; d <<= 1) {
      rs0 += __shfl_xor(rs0, d);
      rs1 += __shfl_xor(rs1, d);
      rs2 += __shfl_xor(rs2, d);
      rs3 += __shfl_xor(rs3, d);
    }
    if (fr < 4) {
      float v = (fr == 0) ? rs0 : (fr == 1) ? rs1 : (fr == 2) ? rs2 : rs3;
      part[wid][mi * 16 + g * 4 + fr] = v;
    }
  }
  __syncthreads();
  if (t < 128) {
    float s = 0.f;
#pragma unroll
    for (int w2 = 0; w2 < 8; ++w2) s += part[w2][t];
    scores[t * 512 + mb] = s;
  }
}

// =======================================================================
// mask + softmax + context chunk. grid 512 = (b, col-chunk of 128).
// =======================================================================
__global__ __launch_bounds__(256)
void softctx_kernel(const float* __restrict__ scores, const void* __restrict__ maskp,
                    const int* __restrict__ flag, const u16* __restrict__ enc_bf,
                    u16* __restrict__ X0bf, u16* __restrict__ c1bf) {
  int bx = blockIdx.x;
  int b = bx >> 2, c = bx & 3;
  int t = threadIdx.x;
  __shared__ float wgt[512];
  __shared__ float redm[4], reds[4];
  __shared__ float ps[4][64][2];
  int l0 = t, l1 = t + 256;
  float s0 = scores[b * 512 + l0], s1 = scores[b * 512 + l1];
  bool isbyte = (*flag != 0);
  bool m0, m1;
  if (isbyte) {
    m0 = ((const uint8_t*)maskp)[b * 512 + l0] != 0;
    m1 = ((const uint8_t*)maskp)[b * 512 + l1] != 0;
  } else {
    m0 = ((const int*)maskp)[b * 512 + l0] != 0;
    m1 = ((const int*)maskp)[b * 512 + l1] != 0;
  }
  float v0 = m0 ? -1e12f : s0;
  float v1 = m1 ? -1e12f : s1;
  float mx = fmaxf(v0, v1);
#pragma unroll
  for (int d = 1; d < 64; d <<= 1) mx = fmaxf(mx, __shfl_xor(mx, d));
  if ((t & 63) == 0) redm[t >> 6] = mx;
  __syncthreads();
  mx = fmaxf(fmaxf(redm[0], redm[1]), fmaxf(redm[2], redm[3]));
  float e0 = __expf(v0 - mx), e1 = __expf(v1 - mx);
  float sm = e0 + e1;
#pragma unroll
  for (int d = 1; d < 64; d <<= 1) sm += __shfl_xor(sm, d);
  if ((t & 63) == 0) reds[t >> 6] = sm;
  __syncthreads();
  sm = reds[0] + reds[1] + reds[2] + reds[3];
  float inv = 1.0f / sm;
  wgt[l0] = e0 * inv;
  wgt[l1] = e1 * inv;
  __syncthreads();
  int cp = t & 63, lq = t >> 6;
  int col = c * 128 + cp * 2;
  float a0 = 0.f, a1 = 0.f;
  for (int l = lq * 128; l < lq * 128 + 128; ++l) {
    float wl = wgt[l];
    if (wl != 0.0f) {
      uint32_t v = *(const uint32_t*)(enc_bf + ((size_t)l * 128 + b) * 512 + col);
      a0 += wl * bfhi2f(v & 0xffffu);
      a1 += wl * __uint_as_float(v & 0xffff0000u);
    }
  }
  ps[lq][cp][0] = a0;
  ps[lq][cp][1] = a1;
  __syncthreads();
  if (t < 64) {
    float r0 = ps[0][t][0] + ps[1][t][0] + ps[2][t][0] + ps[3][t][0];
    float r1 = ps[0][t][1] + ps[1][t][1] + ps[2][t][1] + ps[3][t][1];
    int cc = c * 128 + t * 2;
    uint32_t packed = (uint32_t)f2bf(r0) | ((uint32_t)f2bf(r1) << 16);
    *(uint32_t*)(X0bf + b * 1536 + 512 + cc) = packed;
    *(uint32_t*)(c1bf + b * 1024 + 512 + cc) = packed;
  }
}

// =======================================================================
// GRU layer: GEMM (gate-interleaved W: row 4o+g) + fused combine epilogue.
// grid N/32 = 64 blocks (8 outputs each), block 256 (4 waves x 32 rows).
// =======================================================================
__global__ __launch_bounds__(256)
void gru_gemm_kernel(const u16* __restrict__ X, int ldx, const u16* __restrict__ Wp,
                     const float* __restrict__ biasp, const float* __restrict__ hprev,
                     int K, float* __restrict__ hout, u16* __restrict__ xdst) {
  __shared__ float ct[128][36];
  int n0 = blockIdx.x * 32;
  int t = threadIdx.x, lane = t & 63, w = t >> 6;
  int fr = lane & 15, g = lane >> 4, kof = g * 8;
  f32x4 acc[2][2];
#pragma unroll
  for (int i = 0; i < 2; ++i)
#pragma unroll
    for (int j = 0; j < 2; ++j) acc[i][j] = (f32x4){0.f, 0.f, 0.f, 0.f};
  const u16* Xr0 = X + (size_t)(w * 32 + fr) * ldx;
  const u16* Xr1 = Xr0 + (size_t)16 * ldx;
  const u16* Wr0 = Wp + (size_t)(n0 + fr) * K;
  const u16* Wr1 = Wp + (size_t)(n0 + 16 + fr) * K;
#pragma unroll 4
  for (int kt = 0; kt < K; kt += 32) {
    bf16x8 a0 = *(const bf16x8*)(Xr0 + kt + kof);
    bf16x8 a1 = *(const bf16x8*)(Xr1 + kt + kof);
    bf16x8 b0 = *(const bf16x8*)(Wr0 + kt + kof);
    bf16x8 b1 = *(const bf16x8*)(Wr1 + kt + kof);
    acc[0][0] = __builtin_amdgcn_mfma_f32_16x16x32_bf16(a0, b0, acc[0][0], 0, 0, 0);
    acc[0][1] = __builtin_amdgcn_mfma_f32_16x16x32_bf16(a0, b1, acc[0][1], 0, 0, 0);
    acc[1][0] = __builtin_amdgcn_mfma_f32_16x16x32_bf16(a1, b0, acc[1][0], 0, 0, 0);
    acc[1][1] = __builtin_amdgcn_mfma_f32_16x16x32_bf16(a1, b1, acc[1][1], 0, 0, 0);
  }
#pragma unroll
  for (int mi = 0; mi < 2; ++mi)
#pragma unroll
    for (int ni = 0; ni < 2; ++ni) {
      int col = ni * 16 + fr;
      float vb = biasp[n0 + col];
#pragma unroll
      for (int j = 0; j < 4; ++j)
        ct[w * 32 + 16 * mi + g * 4 + j][col] = acc[mi][ni][j] + vb;
    }
  __syncthreads();
#pragma unroll
  for (int i = 0; i < 4; ++i) {
    int u = t + i * 256;
    int b = u >> 3, ol = u & 7;
    float cr = ct[b][ol * 4 + 0];
    float cz = ct[b][ol * 4 + 1];
    float ci = ct[b][ol * 4 + 2];
    float ch = ct[b][ol * 4 + 3];
    int o = blockIdx.x * 8 + ol;
    float r = fast_sig(cr);
    float z = fast_sig(cz);
    float n = tanhf(ci + r * ch);
    float h = (1.0f - z) * n + z * hprev[b * 512 + o];
    hout[b * 512 + o] = h;
    xdst[b * 1024 + o] = f2bf(h);
  }
}

extern "C" void kernel_launch(void* const* d_in, const int* in_sizes, int n_in,
                              void* d_out, int out_size, void* d_ws, size_t ws_size,
                              hipStream_t stream) {
  const int*   ids    = (const int*)  d_in[0];
  const float* lh     = (const float*)d_in[1];
  const float* wdv    = (const float*)d_in[2];
  const float* enc    = (const float*)d_in[3];
  const void*  mask   = d_in[4];
  const float* attn_W = (const float*)d_in[5];
  const float* attn_b = (const float*)d_in[6];
  const float* scW    = (const float*)d_in[7];
  const float* cat_W  = (const float*)d_in[8];
  const float* cat_b  = (const float*)d_in[9];
  const float* W_ih0  = (const float*)d_in[10];
  const float* W_hh0  = (const float*)d_in[11];
  const float* b_ih0  = (const float*)d_in[12];
  const float* b_hh0  = (const float*)d_in[13];
  const float* W_ih1  = (const float*)d_in[14];
  const float* W_hh1  = (const float*)d_in[15];
  const float* b_ih1  = (const float*)d_in[16];
  const float* b_hh1  = (const float*)d_in[17];

  float* out = (float*)d_out;
  float* h0  = out + 65536;
  float* h1  = out + 131072;

  float* ws     = (float*)d_ws;
  float* scores = ws;                      // 65536
  float* qW     = ws + 65536;              // 65536
  float* biasg0 = ws + 131072;             // 2048
  float* biasg1 = ws + 133120;             // 2048
  int*   flag   = (int*)(ws + 135168);     // 16
  u16*   arena  = (u16*)(ws + 135184);     // 6291456 u16
  u16*   enc_bf = (u16*)(ws + 3280912);    // 33554432 u16
  u16*   X0bf   = (u16*)(ws + 20058128);   // 196608 u16 [emb|ctx|lh0]
  u16*   X1bf   = (u16*)(ws + 20156432);   // 131072 u16 [h0|q]
  u16*   c1bf   = (u16*)(ws + 20221968);   // 131072 u16 [h1|ctx]

  const u16* Whid = arena;
  const u16* Wenc = arena + 262144;
  const u16* Wcat = arena + 524288;
  const u16* Wg0p = arena + 1048576;
  const u16* Wg1p = arena + 4194304;

  prep_all_kernel<<<23313, 256, 0, stream>>>(enc, enc_bf, attn_W, cat_W,
                                             W_ih0, W_hh0, W_ih1, W_hh1,
                                             b_ih0, b_hh0, b_ih1, b_hh1,
                                             arena, biasg0, biasg1,
                                             wdv, ids, lh, X0bf, X1bf,
                                             (const uint8_t*)mask, flag);
  // qW = q @ Whid^T + attn_b  (q bf16 in X1bf[:,512:])
  thin_gemm32<<<16, 256, 0, stream>>>(X1bf + 512, 1024, Whid, attn_b, qW, 512, 512, 0);
  attn_scores_kernel<<<512, 512, 0, stream>>>(enc_bf, Wenc, qW, scW, scores);
  softctx_kernel<<<512, 256, 0, stream>>>(scores, mask, flag, enc_bf, X0bf, c1bf);
  // layer 0: fused GEMM+combine, writes h0 and X1bf[:, :512]
  gru_gemm_kernel<<<64, 256, 0, stream>>>(X0bf, 1536, Wg0p, biasg0, lh, 1536, h0, X1bf);
  // layer 1: writes h1 and c1bf[:, :512]
  gru_gemm_kernel<<<64, 256, 0, stream>>>(X1bf, 1024, Wg1p, biasg1, lh + 65536, 1024, h1, c1bf);
  // output = tanh(c1 @ Wcat^T + cat_b)
  thin_gemm32<<<16, 256, 0, stream>>>(c1bf, 1024, Wcat, cat_b, out, 512, 1024, 1);
}